// Round 15
// baseline (47.578 us; speedup 1.0000x reference)
//
#include <hip/hip_runtime.h>
#include <hip/hip_bf16.h>

#define B_ 8
#define T_ 2048
#define C_ 1024
#define HS_ 64

typedef float f32x4 __attribute__((ext_vector_type(4)));
typedef float f32x16 __attribute__((ext_vector_type(16)));
typedef __bf16 bf16x8 __attribute__((ext_vector_type(8)));
typedef __bf16 bf16x4 __attribute__((ext_vector_type(4)));

__device__ __forceinline__ void gld_lds16(const void* g, void* l) {
    __builtin_amdgcn_global_load_lds(
        (const __attribute__((address_space(1))) void*)g,
        (__attribute__((address_space(3))) void*)l, 16, 0, 0);
}

// Workspaces:
//  wt[192][1024] bf16, pre-swizzled per 64-col k-tile (r14-exact).
//  32x32-MFMA fragment workspaces (lane l, l31=l&31, lh=l>>5, j=0..7):
//   Qf32[qt32g][ks 0..4)[64][8] : word = Q[qt32g*32+l31][ks*16+lh*8+j]  (B-op)
//   Kf32[kt32g][ks 0..4)[64][8] : word = K[kt32g*32+l31][ks*16+lh*8+j]  (A-op)
//   Vf32[kt32g][dt 0..2)[ksl 0..2)[64][8] :
//        word = V[kt32g*32+ksl*16+lh*8+j][dt*32+l31]                    (B-op)
//  qt32g/kt32g = global 32-row index = b*64 + t/32.

// ---------------------------------------------------------------------------
// Kernel 1: W [1024][64] fp32 -> wt [192][1024] bf16 (r14-exact).
// ---------------------------------------------------------------------------
__global__ __launch_bounds__(256) void wt_kernel(const float* __restrict__ Wq,
                                                 const float* __restrict__ Wk,
                                                 const float* __restrict__ Wv,
                                                 __bf16* __restrict__ wt) {
    __shared__ float tile[64][65];
    int mb = blockIdx.x >> 4;
    int k0 = (blockIdx.x & 15) * 64;
    const float* W = (mb == 0) ? Wq : (mb == 1 ? Wk : Wv);
    int c = threadIdx.x & 63;
#pragma unroll
    for (int r = threadIdx.x >> 6; r < 64; r += 4)
        tile[r][c] = W[(size_t)(k0 + r) * 64 + c];
    __syncthreads();
    float scale = (mb == 0) ? 0.03125f : 1.0f;
#pragma unroll
    for (int i = 0; i < 2; ++i) {
        int u = threadIdx.x + i * 256;
        int n  = u >> 3;
        int ch = u & 7;
        int src = (ch ^ (n & 7)) * 8;
        bf16x8 v;
#pragma unroll
        for (int e = 0; e < 8; ++e)
            v[e] = (__bf16)(tile[src + e][n] * scale);
        *(bf16x8*)(wt + (size_t)(mb * 64 + n) * C_ + k0 + ch * 8) = v;
    }
}

// ---------------------------------------------------------------------------
// Kernel 2: QKV GEMM (r14 main loop; epilogue emits 32x32-MFMA fragments).
// 512 blocks x 512 thr. 32 rows x 192 cols, K-step 64.
// ---------------------------------------------------------------------------
__global__ __launch_bounds__(512) void qkv_kernel(const float* __restrict__ x,
                                                  const __bf16* __restrict__ wt,
                                                  __bf16* __restrict__ qf,
                                                  __bf16* __restrict__ kf,
                                                  __bf16* __restrict__ vf) {
    __shared__ __align__(16) char smem[57344];
    __bf16* xs0 = (__bf16*)smem;               // [32][64] swz, 4KB
    __bf16* xs1 = (__bf16*)(smem + 4096);
    __bf16* ws0 = (__bf16*)(smem + 8192);      // [192][64] swz, 24KB
    __bf16* ws1 = (__bf16*)(smem + 32768);

    const int tid = threadIdx.x;
    const int w = tid >> 6, lane = tid & 63, lq = lane & 15, lg = lane >> 4;
    const int l31 = lane & 31, lh = lane >> 5;
    const int m0 = blockIdx.x * 32;
    const int mt = w & 1;
    const int ntb = (w >> 1) * 3;

    f32x4 acc[3];
#pragma unroll
    for (int i = 0; i < 3; ++i) acc[i] = (f32x4)0.0f;

    const int xrow = tid >> 3, xch = tid & 7;
    float4 xr0, xr1;
    const int wslot0 = w * 3 * 64 + lane;

    if (tid < 256) {
        const float* xp = x + (size_t)(m0 + xrow) * C_ + xch * 8;
        xr0 = *(const float4*)xp;
        xr1 = *(const float4*)(xp + 4);
    }
#pragma unroll
    for (int s = 0; s < 3; ++s) {
        int slot = wslot0 + s * 64;
        gld_lds16(wt + (size_t)(slot >> 3) * C_ + (slot & 7) * 8,
                  ws0 + (w * 3 + s) * 512);
    }
    if (tid < 256) {
        bf16x8 xb;
#pragma unroll
        for (int j = 0; j < 4; ++j) { xb[j] = (__bf16)xr0[j]; xb[4 + j] = (__bf16)xr1[j]; }
        *(bf16x8*)(xs0 + xrow * 64 + ((xch ^ (xrow & 7)) * 8)) = xb;
    }

    for (int kt = 0; kt < 16; ++kt) {
        __syncthreads();
        __bf16* xsc = (kt & 1) ? xs1 : xs0;
        __bf16* wsc = (kt & 1) ? ws1 : ws0;
        __bf16* xsn = (kt & 1) ? xs0 : xs1;
        __bf16* wsn = (kt & 1) ? ws0 : ws1;
        if (kt < 15) {
            int k0 = (kt + 1) * 64;
            if (tid < 256) {
                const float* xp = x + (size_t)(m0 + xrow) * C_ + k0 + xch * 8;
                xr0 = *(const float4*)xp;
                xr1 = *(const float4*)(xp + 4);
            }
#pragma unroll
            for (int s = 0; s < 3; ++s) {
                int slot = wslot0 + s * 64;
                gld_lds16(wt + (size_t)(slot >> 3) * C_ + k0 + (slot & 7) * 8,
                          wsn + (w * 3 + s) * 512);
            }
        }
#pragma unroll
        for (int ks = 0; ks < 2; ++ks) {
            int r = mt * 16 + lq;
            bf16x8 a = *(const bf16x8*)(xsc + r * 64 + (((ks * 4 + lg) ^ (r & 7)) * 8));
#pragma unroll
            for (int i = 0; i < 3; ++i) {
                int rw = (ntb + i) * 16 + lq;
                bf16x8 b = *(const bf16x8*)(wsc + rw * 64 + (((ks * 4 + lg) ^ (rw & 7)) * 8));
                acc[i] = __builtin_amdgcn_mfma_f32_16x16x32_bf16(a, b, acc[i], 0, 0, 0);
            }
        }
        if (kt < 15 && tid < 256) {
            bf16x8 xb;
#pragma unroll
            for (int j = 0; j < 4; ++j) { xb[j] = (__bf16)xr0[j]; xb[4 + j] = (__bf16)xr1[j]; }
            *(bf16x8*)(xsn + xrow * 64 + ((xch ^ (xrow & 7)) * 8)) = xb;
        }
    }
    __syncthreads();

    __bf16(*obuf)[208] = (__bf16(*)[208])smem;
#pragma unroll
    for (int i = 0; i < 3; ++i)
#pragma unroll
        for (int r = 0; r < 4; ++r)
            obuf[mt * 16 + lg * 4 + r][(ntb + i) * 16 + lq] = (__bf16)acc[i][r];
    __syncthreads();

    // epilogue: emit 32x32-MFMA fragment layouts
    size_t t32g = (size_t)blockIdx.x;            // == m0 >> 5
    if (w < 4) {
        int ks = w;
        bf16x8 vq = *(const bf16x8*)&obuf[l31][ks * 16 + lh * 8];
        bf16x8 vk = *(const bf16x8*)&obuf[l31][64 + ks * 16 + lh * 8];
        *(bf16x8*)(qf + ((t32g * 4 + ks) * 64 + lane) * 8) = vq;
        *(bf16x8*)(kf + ((t32g * 4 + ks) * 64 + lane) * 8) = vk;
    } else {
        int dt = (w - 4) >> 1, ksl = (w - 4) & 1;
        bf16x8 vv;
#pragma unroll
        for (int j = 0; j < 8; ++j)
            vv[j] = obuf[ksl * 16 + lh * 8 + j][128 + dt * 32 + l31];
        *(bf16x8*)(vf + (((t32g * 2 + dt) * 2 + ksl) * 64 + lane) * 8) = vv;
    }
}

// ---------------------------------------------------------------------------
// Kernel 3: causal flash attention, 32x32 MFMA, Q32 per wave. 512 blocks x
// 8 waves; all waves share the block's 32 queries, kt round-robin stride 8
// over 32-key tiles; swapped QK^T (S^T = K Q^T); defer-max; exp in place;
// bf16 partial-O flash-combine across 8 waves (LDS union with P staging).
// ---------------------------------------------------------------------------
__global__ __launch_bounds__(512, 4) void attn_kernel(const __bf16* __restrict__ qf,
                                                      const __bf16* __restrict__ kf,
                                                      const __bf16* __restrict__ vf,
                                                      float* __restrict__ out) {
    // loop: P staging 8 x [32][36] bf16 (2304B each, region 0..18431)
    // post: olds 8 x [64 dim][32 q] bf16 (4096B each, region 0..32767)
    // mlds/llds at 32768/33792 (disjoint from loop region)
    __shared__ __align__(16) char smem[34816];
    float* mlds = (float*)(smem + 32768);   // [8][32]
    float* llds = (float*)(smem + 33792);   // [8][32]

    const int tid = threadIdx.x;
    const int w = tid >> 6, lane = tid & 63;
    const int l31 = lane & 31, lh = lane >> 5;

    const int b  = blockIdx.x & 7;                 // batch -> XCD affinity
    const int q0 = (63 - (blockIdx.x >> 3)) * 32;  // heavy blocks first

    // Q B-fragments (16 VGPRs): col = query l31, k = dims
    size_t qt32g = (size_t)b * 64 + (q0 >> 5);
    bf16x8 bq[4];
#pragma unroll
    for (int ks = 0; ks < 4; ++ks)
        bq[ks] = *(const bf16x8*)(qf + ((qt32g * 4 + ks) * 64 + lane) * 8);

    f32x16 o2[2];
    o2[0] = (f32x16)0.0f;
    o2[1] = (f32x16)0.0f;
    float m_s = -1e30f, l_s = 0.f;

    __bf16* pP = (__bf16*)(smem + w * 2304);   // [32][36]

    int ntiles = (q0 >> 5) + 1;
    for (int kt = w; kt < ntiles; kt += 8) {
        int s0 = kt * 32;
        size_t kt32g = (size_t)b * 64 + (s0 >> 5);
        // S^T[32 keys][32 q] = K Q^T : 4 chained MFMAs over dims
        f32x16 st = (f32x16)0.0f;
        __builtin_amdgcn_s_setprio(1);
#pragma unroll
        for (int ks = 0; ks < 4; ++ks) {
            bf16x8 ka = *(const bf16x8*)(kf + ((kt32g * 4 + ks) * 64 + lane) * 8);
            st = __builtin_amdgcn_mfma_f32_32x32x16_bf16(ka, bq[ks], st, 0, 0, 0);
        }
        __builtin_amdgcn_s_setprio(0);
        // causal mask: key = s0 + g*8 + 4*lh + r ; query = q0 + l31
        if (s0 + 31 > q0) {
#pragma unroll
            for (int g = 0; g < 4; ++g)
#pragma unroll
                for (int r = 0; r < 4; ++r)
                    if (s0 + g * 8 + 4 * lh + r > q0 + l31) st[g * 4 + r] = -1e30f;
        }
        // V prefetch (B-frags, independent of softmax)
        bf16x8 bv[2][2];
#pragma unroll
        for (int dt = 0; dt < 2; ++dt)
#pragma unroll
            for (int ksl = 0; ksl < 2; ++ksl)
                bv[dt][ksl] = *(const bf16x8*)(vf +
                    (((kt32g * 2 + dt) * 2 + ksl) * 64 + lane) * 8);
        // online softmax for query l31 (16 scores/lane + partner lane)
        float pm = -1e30f;
#pragma unroll
        for (int e = 0; e < 16; ++e) pm = fmaxf(pm, st[e]);
        pm = fmaxf(pm, __shfl_xor(pm, 32));
        bool need = __any(pm > m_s);
        float al = 1.0f;
        if (need) {
            float mn = fmaxf(m_s, pm);
            al = __expf(m_s - mn);
            m_s = mn;
        }
        float rs = 0.f;
#pragma unroll
        for (int e = 0; e < 16; ++e) {
            st[e] = __expf(st[e] - m_s);
            rs += st[e];
        }
        rs += __shfl_xor(rs, 32);
        if (need) {
            l_s = l_s * al + rs;
            // O rows = queries g*8+4*lh+r -> gather al from lane = query idx
#pragma unroll
            for (int g = 0; g < 4; ++g)
#pragma unroll
                for (int r = 0; r < 4; ++r) {
                    float alr = __shfl(al, g * 8 + 4 * lh + r);
                    o2[0][g * 4 + r] *= alr;
                    o2[1][g * 4 + r] *= alr;
                }
        } else {
            l_s += rs;
        }
        // P -> LDS: P[query l31][key rows], 4x bf16x4 stores
#pragma unroll
        for (int g = 0; g < 4; ++g) {
            bf16x4 pk;
#pragma unroll
            for (int r = 0; r < 4; ++r) pk[r] = (__bf16)st[g * 4 + r];
            *(bf16x4*)&pP[l31 * 36 + g * 8 + 4 * lh] = pk;
        }
        asm volatile("" ::: "memory");
        // PV A-frags: row = query l31, k = key ksl*16 + lh*8 + j
        bf16x8 pa0 = *(const bf16x8*)&pP[l31 * 36 + lh * 8];
        bf16x8 pa1 = *(const bf16x8*)&pP[l31 * 36 + 16 + lh * 8];
        __builtin_amdgcn_s_setprio(1);
#pragma unroll
        for (int dt = 0; dt < 2; ++dt) {
            o2[dt] = __builtin_amdgcn_mfma_f32_32x32x16_bf16(pa0, bv[dt][0], o2[dt], 0, 0, 0);
            o2[dt] = __builtin_amdgcn_mfma_f32_32x32x16_bf16(pa1, bv[dt][1], o2[dt], 0, 0, 0);
        }
        __builtin_amdgcn_s_setprio(0);
    }

    // partials: olds[w][dim][query] bf16 (overlays P region)
    __syncthreads();
    __bf16* olds_w = (__bf16*)(smem + w * 4096);
#pragma unroll
    for (int dt = 0; dt < 2; ++dt)
#pragma unroll
        for (int g = 0; g < 4; ++g) {
            bf16x4 pk;
#pragma unroll
            for (int r = 0; r < 4; ++r) pk[r] = (__bf16)o2[dt][g * 4 + r];
            *(bf16x4*)&olds_w[(l31 + dt * 32) * 32 + g * 8 + 4 * lh] = pk;
        }
    if (lh == 0) {
        mlds[w * 32 + l31] = m_s;
        llds[w * 32 + l31] = l_s;
    }
    __syncthreads();

    // flash-combine across 8 waves: thread -> (query, 4 dims)
    int q  = tid >> 4;
    int c4 = (tid & 15) * 4;
    float M = -1e30f;
#pragma unroll
    for (int w2 = 0; w2 < 8; ++w2) M = fmaxf(M, mlds[w2 * 32 + q]);
    float L = 0.f;
    f32x4 oa = (f32x4)0.0f;
#pragma unroll
    for (int w2 = 0; w2 < 8; ++w2) {
        float sc = __expf(mlds[w2 * 32 + q] - M);
        L += sc * llds[w2 * 32 + q];
        const __bf16* op = (const __bf16*)(smem + w2 * 4096);
#pragma unroll
        for (int k = 0; k < 4; ++k)
            oa[k] += sc * (float)op[(c4 + k) * 32 + q];
    }
    float inv = 1.0f / L;
    float4 stv;
    stv.x = oa[0] * inv; stv.y = oa[1] * inv; stv.z = oa[2] * inv; stv.w = oa[3] * inv;
    *(float4*)(out + ((size_t)b * T_ + q0 + q) * HS_ + c4) = stv;
}

extern "C" void kernel_launch(void* const* d_in, const int* in_sizes, int n_in,
                              void* d_out, int out_size, void* d_ws, size_t ws_size,
                              hipStream_t stream) {
    const float* x  = (const float*)d_in[0];
    const float* Wq = (const float*)d_in[1];
    const float* Wk = (const float*)d_in[2];
    const float* Wv = (const float*)d_in[3];
    char* ws = (char*)d_ws;
    __bf16* wt = (__bf16*)ws;                     // 393216 B
    __bf16* qf = (__bf16*)(ws + 393216);          // 2 MB (Qf32)
    __bf16* kf = (__bf16*)(ws + 2490368);         // 2 MB (Kf32)
    __bf16* vf = (__bf16*)(ws + 4587520);         // 2 MB (Vf32)
    float* out = (float*)d_out;

    wt_kernel<<<dim3(48), dim3(256), 0, stream>>>(Wq, Wk, Wv, wt);
    qkv_kernel<<<dim3(512), dim3(512), 0, stream>>>(x, wt, qf, kf, vf);
    attn_kernel<<<dim3(512), dim3(512), 0, stream>>>(qf, kf, vf, out);
}

// Round 16
// 39.101 us; speedup vs baseline: 1.2168x; 1.2168x over previous
//
#include <hip/hip_runtime.h>
#include <hip/hip_bf16.h>

#define B_ 8
#define T_ 2048
#define C_ 1024
#define HS_ 64

typedef float f32x4 __attribute__((ext_vector_type(4)));
typedef __bf16 bf16x8 __attribute__((ext_vector_type(8)));
typedef __bf16 bf16x4 __attribute__((ext_vector_type(4)));

__device__ __forceinline__ void gld_lds16(const void* g, void* l) {
    __builtin_amdgcn_global_load_lds(
        (const __attribute__((address_space(1))) void*)g,
        (__attribute__((address_space(3))) void*)l, 16, 0, 0);
}

// Workspaces:
//  wt[192][1024] bf16, PRE-SWIZZLED per 64-col k-tile: chunk c (16B) of row
//  rw holds original chunk c^(rw&7) (rule #21: source perm == read perm).
//  Rows 0-63 Wq^T (scaled 1/32), 64-127 Wk^T, 128-191 Wv^T.
//  Qf[b*128+qt16][2 half][64 lane][8] : word = Q[qt*16+(lane&15)][half*32+(lane>>4)*8+j]
//  Kf identical mapping. Vf[b*64+kt32][4 ntv][64][8]:
//  word = V[kt32*32+(lane>>4)*8+j][ntv*16+(lane&15)]

// ---------------------------------------------------------------------------
// Kernel 1: W [1024][64] fp32 -> wt [192][1024] bf16, transposed, q scaled,
// chunk-swizzled, vectorized 16B stores.
// ---------------------------------------------------------------------------
__global__ __launch_bounds__(256) void wt_kernel(const float* __restrict__ Wq,
                                                 const float* __restrict__ Wk,
                                                 const float* __restrict__ Wv,
                                                 __bf16* __restrict__ wt) {
    __shared__ float tile[64][65];
    int mb = blockIdx.x >> 4;
    int k0 = (blockIdx.x & 15) * 64;
    const float* W = (mb == 0) ? Wq : (mb == 1 ? Wk : Wv);
    int c = threadIdx.x & 63;
#pragma unroll
    for (int r = threadIdx.x >> 6; r < 64; r += 4)
        tile[r][c] = W[(size_t)(k0 + r) * 64 + c];
    __syncthreads();
    float scale = (mb == 0) ? 0.03125f : 1.0f;
#pragma unroll
    for (int i = 0; i < 2; ++i) {
        int u = threadIdx.x + i * 256;   // 0..511 = 64 rows x 8 chunks
        int n  = u >> 3;
        int ch = u & 7;
        int src = (ch ^ (n & 7)) * 8;
        bf16x8 v;
#pragma unroll
        for (int e = 0; e < 8; ++e)
            v[e] = (__bf16)(tile[src + e][n] * scale);
        *(bf16x8*)(wt + (size_t)(mb * 64 + n) * C_ + k0 + ch * 8) = v;
    }
}

// ---------------------------------------------------------------------------
// Kernel 2: QKV GEMM. 512 blocks x 512 thr. 32 rows x 192 cols, K-step 64,
// W via global_load_lds from pre-swizzled wt, x reg-staged.
// ---------------------------------------------------------------------------
__global__ __launch_bounds__(512) void qkv_kernel(const float* __restrict__ x,
                                                  const __bf16* __restrict__ wt,
                                                  __bf16* __restrict__ qf,
                                                  __bf16* __restrict__ kf,
                                                  __bf16* __restrict__ vf) {
    __shared__ __align__(16) char smem[57344];
    __bf16* xs0 = (__bf16*)smem;               // [32][64] swz, 4KB
    __bf16* xs1 = (__bf16*)(smem + 4096);
    __bf16* ws0 = (__bf16*)(smem + 8192);      // [192][64] swz, 24KB
    __bf16* ws1 = (__bf16*)(smem + 32768);

    const int tid = threadIdx.x;
    const int w = tid >> 6, lane = tid & 63, lq = lane & 15, lg = lane >> 4;
    const int m0 = blockIdx.x * 32;
    const int mt = w & 1;
    const int ntb = (w >> 1) * 3;

    f32x4 acc[3];
#pragma unroll
    for (int i = 0; i < 3; ++i) acc[i] = (f32x4)0.0f;

    const int xrow = tid >> 3, xch = tid & 7;
    float4 xr0, xr1;
    const int wslot0 = w * 3 * 64 + lane;

    if (tid < 256) {
        const float* xp = x + (size_t)(m0 + xrow) * C_ + xch * 8;
        xr0 = *(const float4*)xp;
        xr1 = *(const float4*)(xp + 4);
    }
#pragma unroll
    for (int s = 0; s < 3; ++s) {
        int slot = wslot0 + s * 64;
        gld_lds16(wt + (size_t)(slot >> 3) * C_ + (slot & 7) * 8,
                  ws0 + (w * 3 + s) * 512);
    }
    if (tid < 256) {
        bf16x8 xb;
#pragma unroll
        for (int j = 0; j < 4; ++j) { xb[j] = (__bf16)xr0[j]; xb[4 + j] = (__bf16)xr1[j]; }
        *(bf16x8*)(xs0 + xrow * 64 + ((xch ^ (xrow & 7)) * 8)) = xb;
    }

    for (int kt = 0; kt < 16; ++kt) {
        __syncthreads();
        __bf16* xsc = (kt & 1) ? xs1 : xs0;
        __bf16* wsc = (kt & 1) ? ws1 : ws0;
        __bf16* xsn = (kt & 1) ? xs0 : xs1;
        __bf16* wsn = (kt & 1) ? ws0 : ws1;
        if (kt < 15) {
            int k0 = (kt + 1) * 64;
            if (tid < 256) {
                const float* xp = x + (size_t)(m0 + xrow) * C_ + k0 + xch * 8;
                xr0 = *(const float4*)xp;
                xr1 = *(const float4*)(xp + 4);
            }
#pragma unroll
            for (int s = 0; s < 3; ++s) {
                int slot = wslot0 + s * 64;
                gld_lds16(wt + (size_t)(slot >> 3) * C_ + k0 + (slot & 7) * 8,
                          wsn + (w * 3 + s) * 512);
            }
        }
#pragma unroll
        for (int ks = 0; ks < 2; ++ks) {
            int r = mt * 16 + lq;
            bf16x8 a = *(const bf16x8*)(xsc + r * 64 + (((ks * 4 + lg) ^ (r & 7)) * 8));
#pragma unroll
            for (int i = 0; i < 3; ++i) {
                int rw = (ntb + i) * 16 + lq;
                bf16x8 b = *(const bf16x8*)(wsc + rw * 64 + (((ks * 4 + lg) ^ (rw & 7)) * 8));
                acc[i] = __builtin_amdgcn_mfma_f32_16x16x32_bf16(a, b, acc[i], 0, 0, 0);
            }
        }
        if (kt < 15 && tid < 256) {
            bf16x8 xb;
#pragma unroll
            for (int j = 0; j < 4; ++j) { xb[j] = (__bf16)xr0[j]; xb[4 + j] = (__bf16)xr1[j]; }
            *(bf16x8*)(xsn + xrow * 64 + ((xch ^ (xrow & 7)) * 8)) = xb;
        }
    }
    __syncthreads();

    __bf16(*obuf)[208] = (__bf16(*)[208])smem;
#pragma unroll
    for (int i = 0; i < 3; ++i)
#pragma unroll
        for (int r = 0; r < 4; ++r)
            obuf[mt * 16 + lg * 4 + r][(ntb + i) * 16 + lq] = (__bf16)acc[i][r];
    __syncthreads();

    if (w < 4) {
        int mg = w & 1, half = w >> 1;
        size_t qt16 = (size_t)(m0 >> 4) + mg;
        bf16x8 vq = *(const bf16x8*)&obuf[mg * 16 + lq][half * 32 + lg * 8];
        bf16x8 vk = *(const bf16x8*)&obuf[mg * 16 + lq][64 + half * 32 + lg * 8];
        *(bf16x8*)(qf + ((qt16 * 2 + half) * 64 + lane) * 8) = vq;
        *(bf16x8*)(kf + ((qt16 * 2 + half) * 64 + lane) * 8) = vk;
    } else {
        int ntv = w - 4;
        bf16x8 vv;
#pragma unroll
        for (int j = 0; j < 8; ++j)
            vv[j] = obuf[lg * 8 + j][128 + ntv * 16 + lq];
        size_t kt32 = (size_t)(m0 >> 5);
        *(bf16x8*)(vf + ((kt32 * 4 + ntv) * 64 + lane) * 8) = vv;
    }
}

// ---------------------------------------------------------------------------
// Kernel 3: causal flash attention (best-measured config). 512 blocks x 8
// waves; wave-paired Q32; swapped QK^T; KVBLK=64; defer-max; V-prefetch;
// flash-combine per 4-wave half.
// ---------------------------------------------------------------------------
__global__ __launch_bounds__(512, 4) void attn_kernel(const __bf16* __restrict__ qf,
                                                      const __bf16* __restrict__ kf,
                                                      const __bf16* __restrict__ vf,
                                                      float* __restrict__ out) {
    __shared__ float olds[8][16][64];
    __shared__ float mlds[8][16], llds[8][16];
    __shared__ __align__(16) __bf16 plds[8][16 * 72];

    int w    = threadIdx.x >> 6;
    int lane = threadIdx.x & 63;
    int lq = lane & 15, lg = lane >> 4;

    int b  = blockIdx.x & 7;
    int q0 = (63 - (blockIdx.x >> 3)) * 32;
    int qs = w >> 2;
    int wk = w & 3;
    int qt = q0 + qs * 16;

    size_t qbase = ((size_t)b * 128 + (qt >> 4)) * 2;
    bf16x8 aq0 = *(const bf16x8*)(qf + ((qbase + 0) * 64 + lane) * 8);
    bf16x8 aq1 = *(const bf16x8*)(qf + ((qbase + 1) * 64 + lane) * 8);

    f32x4 o[4];
#pragma unroll
    for (int nt = 0; nt < 4; ++nt) o[nt] = (f32x4)0.0f;
    float m_s = -1e30f, l_s = 0.f;

    __bf16* pw = &plds[w][0];

    int ntiles = (qt + 79) >> 6;
    for (int kt = wk; kt < ntiles; kt += 4) {
        int s0 = kt * 64;
        f32x4 s[4];
        __builtin_amdgcn_s_setprio(1);
#pragma unroll
        for (int ct = 0; ct < 4; ++ct) {
            size_t kbase = ((size_t)b * 128 + (s0 >> 4) + ct) * 2;
            bf16x8 k0 = *(const bf16x8*)(kf + ((kbase + 0) * 64 + lane) * 8);
            bf16x8 k1 = *(const bf16x8*)(kf + ((kbase + 1) * 64 + lane) * 8);
            f32x4 a = (f32x4)0.0f;
            a = __builtin_amdgcn_mfma_f32_16x16x32_bf16(k0, aq0, a, 0, 0, 0);
            a = __builtin_amdgcn_mfma_f32_16x16x32_bf16(k1, aq1, a, 0, 0, 0);
            s[ct] = a;
        }
        __builtin_amdgcn_s_setprio(0);
        if (s0 + 63 > qt) {
#pragma unroll
            for (int ct = 0; ct < 4; ++ct)
#pragma unroll
                for (int r = 0; r < 4; ++r)
                    if (s0 + ct * 16 + lg * 4 + r > qt + lq) s[ct][r] = -1e30f;
        }
        bf16x8 bv[2][4];
#pragma unroll
        for (int ks = 0; ks < 2; ++ks)
#pragma unroll
            for (int nt = 0; nt < 4; ++nt)
                bv[ks][nt] = *(const bf16x8*)(vf +
                    (((size_t)(b * 64 + (s0 >> 5) + ks) * 4 + nt) * 64 + lane) * 8);
        float pm = -1e30f;
#pragma unroll
        for (int ct = 0; ct < 4; ++ct)
#pragma unroll
            for (int r = 0; r < 4; ++r) pm = fmaxf(pm, s[ct][r]);
        pm = fmaxf(pm, __shfl_xor(pm, 16));
        pm = fmaxf(pm, __shfl_xor(pm, 32));
        bool need = __any(pm > m_s);
        float al = 1.0f;
        if (need) {
            float mn = fmaxf(m_s, pm);
            al = __expf(m_s - mn);
            m_s = mn;
        }
        float rs = 0.f;
        f32x4 p[4];
#pragma unroll
        for (int ct = 0; ct < 4; ++ct)
#pragma unroll
            for (int r = 0; r < 4; ++r) {
                p[ct][r] = __expf(s[ct][r] - m_s);
                rs += p[ct][r];
            }
        rs += __shfl_xor(rs, 16);
        rs += __shfl_xor(rs, 32);
        if (need) {
            l_s = l_s * al + rs;
            float alr[4];
#pragma unroll
            for (int r = 0; r < 4; ++r) alr[r] = __shfl(al, lg * 4 + r);
#pragma unroll
            for (int nt = 0; nt < 4; ++nt)
#pragma unroll
                for (int r = 0; r < 4; ++r) o[nt][r] *= alr[r];
        } else {
            l_s += rs;
        }
#pragma unroll
        for (int ct = 0; ct < 4; ++ct) {
            bf16x4 qv;
#pragma unroll
            for (int r = 0; r < 4; ++r) qv[r] = (__bf16)p[ct][r];
            *(bf16x4*)&pw[lq * 72 + ct * 16 + lg * 4] = qv;
        }
        asm volatile("" ::: "memory");
        bf16x8 pa0 = *(const bf16x8*)&pw[lq * 72 + lg * 8];
        bf16x8 pa1 = *(const bf16x8*)&pw[lq * 72 + 32 + lg * 8];
        __builtin_amdgcn_s_setprio(1);
#pragma unroll
        for (int nt = 0; nt < 4; ++nt) {
            o[nt] = __builtin_amdgcn_mfma_f32_16x16x32_bf16(pa0, bv[0][nt], o[nt], 0, 0, 0);
            o[nt] = __builtin_amdgcn_mfma_f32_16x16x32_bf16(pa1, bv[1][nt], o[nt], 0, 0, 0);
        }
        __builtin_amdgcn_s_setprio(0);
    }

    asm volatile("" ::: "memory");
#pragma unroll
    for (int nt = 0; nt < 4; ++nt)
#pragma unroll
        for (int r = 0; r < 4; ++r)
            olds[w][lg * 4 + r][nt * 16 + lq] = o[nt][r];
    if (lg == 0) {
        mlds[w][lq] = m_s;
        llds[w][lq] = l_s;
    }
    __syncthreads();

    int row = threadIdx.x >> 4;
    int c4  = (threadIdx.x & 15) * 4;
    int wb  = (row >> 4) * 4;
    int r16 = row & 15;
    float M = -1e30f;
#pragma unroll
    for (int w2 = 0; w2 < 4; ++w2) M = fmaxf(M, mlds[wb + w2][r16]);
    float L = 0.f;
    f32x4 oa = (f32x4)0.0f;
#pragma unroll
    for (int w2 = 0; w2 < 4; ++w2) {
        float sc = __expf(mlds[wb + w2][r16] - M);
        L += sc * llds[wb + w2][r16];
        const float* op = &olds[wb + w2][r16][c4];
#pragma unroll
        for (int j = 0; j < 4; ++j) oa[j] += sc * op[j];
    }
    float inv = 1.0f / L;
    float4 st;
    st.x = oa[0] * inv; st.y = oa[1] * inv; st.z = oa[2] * inv; st.w = oa[3] * inv;
    *(float4*)(out + ((size_t)b * T_ + q0 + row) * HS_ + c4) = st;
}

extern "C" void kernel_launch(void* const* d_in, const int* in_sizes, int n_in,
                              void* d_out, int out_size, void* d_ws, size_t ws_size,
                              hipStream_t stream) {
    const float* x  = (const float*)d_in[0];
    const float* Wq = (const float*)d_in[1];
    const float* Wk = (const float*)d_in[2];
    const float* Wv = (const float*)d_in[3];
    char* ws = (char*)d_ws;
    __bf16* wt = (__bf16*)ws;                     // 393216 B
    __bf16* qf = (__bf16*)(ws + 393216);          // 2 MB
    __bf16* kf = (__bf16*)(ws + 2490368);         // 2 MB
    __bf16* vf = (__bf16*)(ws + 4587520);         // 2 MB
    float* out = (float*)d_out;

    wt_kernel<<<dim3(48), dim3(256), 0, stream>>>(Wq, Wk, Wv, wt);
    qkv_kernel<<<dim3(512), dim3(512), 0, stream>>>(x, wt, qf, kf, vf);
    attn_kernel<<<dim3(512), dim3(512), 0, stream>>>(qf, kf, vf, out);
}